// Round 13
// baseline (133.390 us; speedup 1.0000x reference)
//
#include <hip/hip_runtime.h>
#include <hip/hip_bf16.h>
#include <stdint.h>

#define T_LEN 8192
#define DIN   1024
#define DOUT  1024
#define TRACE 64
#define CTX   16
#define KTOT  3072      // DIN + 2*TRACE*CTX
#define CH    64        // scan chunk length
#define NCHUNK 128      // T_LEN / CH
#define WPLD  1032      // padded Wp LDS row (shorts): lane stride 2064B -> 2-way (free)

#define AS1 __attribute__((address_space(1)))
#define AS3 __attribute__((address_space(3)))

// Compile-time-fenced barrier (r9 race fix: intrinsic barrier is not a compiler fence).
#define BAR() asm volatile("s_barrier" ::: "memory")

using bf16 = __hip_bfloat16;
typedef __attribute__((ext_vector_type(4))) float f32x4;
typedef __attribute__((ext_vector_type(8))) short s16x8;

__device__ __forceinline__ void pack4(const float4 v, void* dst) {
    union { bf16 h[4]; uint2 u; } pk;
    pk.h[0] = __float2bfloat16(v.x); pk.h[1] = __float2bfloat16(v.y);
    pk.h[2] = __float2bfloat16(v.z); pk.h[3] = __float2bfloat16(v.w);
    *(uint2*)dst = pk.u;
}

__device__ __forceinline__ uint4 pack8(const float4 a, const float4 b) {
    union { bf16 h[8]; uint4 u; } pk;
    pk.h[0] = __float2bfloat16(a.x); pk.h[1] = __float2bfloat16(a.y);
    pk.h[2] = __float2bfloat16(a.z); pk.h[3] = __float2bfloat16(a.w);
    pk.h[4] = __float2bfloat16(b.x); pk.h[5] = __float2bfloat16(b.y);
    pk.h[6] = __float2bfloat16(b.z); pk.h[7] = __float2bfloat16(b.w);
    return pk.u;
}

// ---------------- tiny: W_pre -> Wp bf16 ----------------
__global__ void cvt_wp(const float* __restrict__ Wpre, bf16* __restrict__ Wp) {
    int idx = blockIdx.x * 256 + threadIdx.x;   // 16384 quads
    int r = idx >> 8, c4 = (idx & 255) << 2;
    pack4(*(const float4*)(Wpre + (size_t)r * 1024 + c4), Wp + (size_t)r * 1024 + c4);
}

// ---------------- fused: x cvt + pre-GEMM + scan phase 1 ----------------
// Reads f32 x directly (kills cvt_all's x pass + the bf16 re-read): reg-stage,
// convert, write A(bf16) + LDS, MFMA vs LDS-resident Wp (preloaded once).
__global__ __launch_bounds__(256) void pre_scan1(
    const float* __restrict__ x,    // [8192][1024] f32
    const bf16* __restrict__ Wp,    // [64][1024] bf16
    bf16* __restrict__ A,           // [8192][KTOT] — x-part written here
    const float* __restrict__ bpre,
    const int* __restrict__ start,
    const float* __restrict__ a, const float* __restrict__ bfreq,
    float* __restrict__ pre_raw,    // [8192][64]
    float2* __restrict__ local_end, // [128][1024]
    int* __restrict__ reset_any) {  // [128]
    __shared__ short Ws[64 * WPLD];     // 132096 B — all of W_pre, padded rows
    __shared__ short As[2][64 * 32];    // 8 KB
    __shared__ float pn[CH][TRACE + 1];
    __shared__ float rn[CH];
    __shared__ int sf[CH];
    const int tid = threadIdx.x, lane = tid & 63, wv = tid >> 6;
    const int row0 = blockIdx.x * 64;

    // ---- one-time Wp preload: wave wv rows [wv*16, wv*16+16), 2 half-rows each ----
    for (int rr = 0; rr < 16; ++rr) {
        int row = wv * 16 + rr;
#pragma unroll
        for (int h = 0; h < 2; ++h) {
            const bf16* src = Wp + (size_t)row * 1024 + h * 512 + lane * 8;
            __builtin_amdgcn_global_load_lds((const AS1 void*)src,
                (AS3 void*)&Ws[row * WPLD + h * 512], 16, 0, 0);
        }
    }

    // ---- A-side mapping: thread t covers row r = t>>2, cols c0 = (t&3)*8 (8 f32/step) ----
    const int r  = tid >> 2;
    const int c0 = (tid & 3) * 8;
    const float* xrow = x + (size_t)(row0 + r) * 1024;
    bf16* arow = A + (size_t)(row0 + r) * KTOT;

    f32x4 acc[4];
#pragma unroll
    for (int j = 0; j < 4; ++j) acc[j] = (f32x4)0.0f;

    float4 cur0 = *(const float4*)(xrow + c0);
    float4 cur1 = *(const float4*)(xrow + c0 + 4);

    asm volatile("s_waitcnt vmcnt(0)" ::: "memory");  // Wp landed (and cur)
    BAR();

    const int lr = lane & 15, lk = (lane >> 4) * 8;
    int buf = 0;
    for (int kt = 0; kt < 32; ++kt) {
        float4 nxt0, nxt1;
        if (kt + 1 < 32) {
            nxt0 = *(const float4*)(xrow + (kt + 1) * 32 + c0);
            nxt1 = *(const float4*)(xrow + (kt + 1) * 32 + c0 + 4);
        }
        uint4 pk = pack8(cur0, cur1);
        *(uint4*)&As[buf][r * 32 + c0] = pk;             // LDS for MFMA
        *(uint4*)(arow + kt * 32 + c0) = pk;             // global A (bf16 x)
        asm volatile("s_waitcnt lgkmcnt(0)" ::: "memory");  // ds_write visible
        BAR();
        s16x8 af = *(const s16x8*)&As[buf][(wv * 16 + lr) * 32 + lk];
        s16x8 bfr[4];
#pragma unroll
        for (int j = 0; j < 4; ++j)
            bfr[j] = *(const s16x8*)&Ws[(j * 16 + lr) * WPLD + kt * 32 + lk];
#pragma unroll
        for (int j = 0; j < 4; ++j)
            acc[j] = __builtin_amdgcn_mfma_f32_16x16x32_bf16(af, bfr[j], acc[j], 0, 0, 0);
        asm volatile("s_waitcnt lgkmcnt(0)" ::: "memory");  // my reads done (WAR close)
        BAR();
        cur0 = nxt0; cur1 = nxt1;
        buf ^= 1;
    }
    const int lg = lane >> 4;
#pragma unroll
    for (int j = 0; j < 4; ++j) {
        int col = j * 16 + lr;
        float bias = bpre[col];
#pragma unroll
        for (int q = 0; q < 4; ++q) {
            int rl = wv * 16 + lg * 4 + q;
            float v = acc[j][q] + bias;
            pn[rl][col] = v;
            pre_raw[(size_t)(row0 + rl) * TRACE + col] = v;
        }
    }
    if (tid < CH) sf[tid] = start[row0 + tid];
    __syncthreads();
    if (tid < CH) {
        float s = 0.f;
#pragma unroll
        for (int m = 0; m < TRACE; ++m) { float v = pn[tid][m]; s += v * v; }
        rn[tid] = 1.0f / (1e-6f + sqrtf(s));
        int any = __any(sf[tid] != 0);
        if (tid == 0) reset_any[blockIdx.x] = any;
    }
    __syncthreads();
#pragma unroll
    for (int q = 0; q < 4; ++q) {
        int pair = tid + q * 256;
        int m = pair >> 4, c = pair & 15;
        float am = a[m], th = bfreq[c];
        float e = expf(-fabsf(am));
        float sn, cs; sincosf(th, &sn, &cs);
        float gr = e * cs, gi = e * sn;
        float sre = 0.f, sim = 0.f;
        for (int rr = 0; rr < CH; ++rr) {
            float p = pn[rr][m] * rn[rr];
            if (sf[rr]) { sre = p; sim = 0.f; }
            else { float t = gr * sre - gi * sim + p; sim = gr * sim + gi * sre; sre = t; }
        }
        local_end[(size_t)blockIdx.x * 1024 + pair] = make_float2(sre, sim);
    }
}

// ---------------- scan phase 2 (blocks 0-15) + weight cvt (blocks 16+) ----------------
// Carry chain uses 16 CUs; the other ~240 CUs convert W_skip/W_mix -> Bc for free.
__global__ void scan_phase2w(const float2* __restrict__ local_end, const int* __restrict__ reset_any,
                             const float* __restrict__ state_re, const float* __restrict__ state_im,
                             const float* __restrict__ a, const float* __restrict__ bfreq,
                             float2* __restrict__ carry_in, float* __restrict__ out_tail, int tail_n,
                             const float* __restrict__ Wsk, const float* __restrict__ Wmx,
                             bf16* __restrict__ Bc) {
    if (blockIdx.x >= 16) {
        int idx = (blockIdx.x - 16) * 256 + threadIdx.x;  // 786432 quads
        if (idx < 262144) {                // W_skip: 1024x1024 -> Bc (coff 0)
            int r = idx >> 8, c4 = (idx & 255) << 2;
            pack4(*(const float4*)(Wsk + (size_t)r * 1024 + c4), Bc + (size_t)r * KTOT + c4);
        } else {                           // W_mix: 1024x2048 -> Bc (coff 1024)
            int i = idx - 262144;
            int r = i >> 9, c4 = (i & 511) << 2;
            pack4(*(const float4*)(Wmx + (size_t)r * 2048 + c4), Bc + (size_t)r * KTOT + 1024 + c4);
        }
        return;
    }
    if (threadIdx.x >= 64) return;
    const int pair = blockIdx.x * 64 + threadIdx.x;  // 16*64 = 1024
    const int m = pair >> 4, c = pair & 15;
    float am = a[m], th = bfreq[c];
    float e = expf(-64.f * fabsf(am));
    float sn, cs; sincosf(64.f * th, &sn, &cs);
    float gr = e * cs, gi = e * sn;
    float cre = state_re[pair], cim = state_im[pair];

    float2 pf[8]; int rsv[8];
#pragma unroll
    for (int j = 0; j < 8; ++j) { pf[j] = local_end[(size_t)j * 1024 + pair]; rsv[j] = reset_any[j]; }
    for (int kb = 0; kb < NCHUNK; kb += 8) {
        float2 cur[8]; int rs[8];
#pragma unroll
        for (int j = 0; j < 8; ++j) { cur[j] = pf[j]; rs[j] = rsv[j]; }
        if (kb + 8 < NCHUNK) {
#pragma unroll
            for (int j = 0; j < 8; ++j) {
                pf[j]  = local_end[(size_t)(kb + 8 + j) * 1024 + pair];
                rsv[j] = reset_any[kb + 8 + j];
            }
        }
#pragma unroll
        for (int j = 0; j < 8; ++j) {
            carry_in[(size_t)(kb + j) * 1024 + pair] = make_float2(cre, cim);
            if (rs[j]) { cre = cur[j].x; cim = cur[j].y; }
            else {
                float t = gr * cre - gi * cim + cur[j].x;
                cim = gr * cim + gi * cre + cur[j].y;
                cre = t;
            }
        }
    }
    if (pair < tail_n)        out_tail[pair]        = cre;
    if (1024 + pair < tail_n) out_tail[1024 + pair] = cim;
}

// ---------------- scan phase 3: recompute with carry, emit bf16 z_in (4B stores) ----------------
__global__ void scan_phase3(const float* __restrict__ pre_raw, const int* __restrict__ start,
                            const float* __restrict__ a, const float* __restrict__ bfreq,
                            const float2* __restrict__ carry_in, bf16* __restrict__ A) {
    __shared__ float pn[CH][TRACE + 1];
    __shared__ float rn[CH];
    __shared__ int sf[CH];
    const int k = blockIdx.x, tid = threadIdx.x;
    for (int idx = tid; idx < CH * TRACE; idx += 256) {
        int r = idx >> 6, m = idx & 63;
        pn[r][m] = pre_raw[(size_t)(k * CH + r) * TRACE + m];
    }
    if (tid < CH) sf[tid] = start[k * CH + tid];
    __syncthreads();
    if (tid < CH) {
        float s = 0.f;
#pragma unroll
        for (int m = 0; m < TRACE; ++m) { float v = pn[tid][m]; s += v * v; }
        rn[tid] = 1.0f / (1e-6f + sqrtf(s));
    }
    __syncthreads();
#pragma unroll
    for (int q = 0; q < 2; ++q) {
        int p0 = q * 512 + tid * 2;           // even pair: handles (m, c0) and (m, c0+1)
        int m = p0 >> 4, c0 = p0 & 15;
        float am = a[m];
        float e = expf(-fabsf(am));
        float sn0, cs0, sn1, cs1;
        sincosf(bfreq[c0], &sn0, &cs0);
        sincosf(bfreq[c0 + 1], &sn1, &cs1);
        float gr0 = e * cs0, gi0 = e * sn0;
        float gr1 = e * cs1, gi1 = e * sn1;
        float4 ci = *(const float4*)&carry_in[(size_t)k * 1024 + p0];
        float sre0 = ci.x, sim0 = ci.y, sre1 = ci.z, sim1 = ci.w;
        for (int r = 0; r < CH; ++r) {
            float p = pn[r][m] * rn[r];
            if (sf[r]) { sre0 = p; sim0 = 0.f; sre1 = p; sim1 = 0.f; }
            else {
                float t0 = gr0 * sre0 - gi0 * sim0 + p; sim0 = gr0 * sim0 + gi0 * sre0; sre0 = t0;
                float t1 = gr1 * sre1 - gi1 * sim1 + p; sim1 = gr1 * sim1 + gi1 * sre1; sre1 = t1;
            }
            size_t off = (size_t)(k * CH + r) * KTOT + 1024 + m * 32;
            union { bf16 h[2]; uint32_t u; } pr, pi;
            pr.h[0] = __float2bfloat16(sre0); pr.h[1] = __float2bfloat16(sre1);
            pi.h[0] = __float2bfloat16(sim0); pi.h[1] = __float2bfloat16(sim1);
            *(uint32_t*)(A + off + c0)      = pr.u;
            *(uint32_t*)(A + off + 16 + c0) = pi.u;
        }
    }
}

// ---------------- main GEMM (unchanged r10 structure) ----------------
__global__ __launch_bounds__(512) void gemm_main(const bf16* __restrict__ A,  // [8192][3072]
                                                 const bf16* __restrict__ B,  // [1024][3072]
                                                 const float* __restrict__ bskip,
                                                 const float* __restrict__ bmix,
                                                 float* __restrict__ out) {   // [8192][1024]
    __shared__ short As[3][256 * 64];   // 96 KB
    __shared__ short Bs[3][128 * 64];   // 48 KB
    const int tid = threadIdx.x;
    const int lane = tid & 63, wv = tid >> 6;
    const int wm = wv >> 1, wn = wv & 1;
    const int wg = blockIdx.x;
    const int xcd = wg & 7, bidx = wg >> 3;          // HW round-robins wg across XCDs
    const int row0 = (xcd * 4 + (bidx >> 3)) * 256;  // 32 row tiles
    const int col0 = (bidx & 7) * 128;               // 8 col tiles

    const int rl8 = lane >> 3;
    const int u8  = lane & 7;
    const int ksw = (u8 ^ rl8) << 3;

    auto stageBatch = [&](int su, int bd, int sb) {
#pragma unroll
        for (int jj = 0; jj < 2; ++jj) {
            int j = sb * 2 + jj;
            int r = wv * 32 + j * 8 + rl8;
            const bf16* ga = A + (size_t)(row0 + r) * KTOT + su * 64 + ksw;
            __builtin_amdgcn_global_load_lds((const AS1 void*)ga,
                (AS3 void*)&As[bd][(wv * 32 + j * 8) * 64], 16, 0, 0);
        }
        int rb = wv * 16 + sb * 8 + rl8;
        const bf16* gb = B + (size_t)(col0 + rb) * KTOT + su * 64 + ksw;
        __builtin_amdgcn_global_load_lds((const AS1 void*)gb,
            (AS3 void*)&Bs[bd][(wv * 16 + sb * 8) * 64], 16, 0, 0);
    };

    f32x4 acc[4][4];
#pragma unroll
    for (int i = 0; i < 4; ++i)
#pragma unroll
        for (int j = 0; j < 4; ++j) acc[i][j] = (f32x4)0.0f;

    const int lr = lane & 15, hi = lane >> 4;
    const int sw0 = ((0 + hi) ^ (lr & 7)) << 3;
    const int sw1 = ((4 + hi) ^ (lr & 7)) << 3;

    s16x8 af[4][2], bfr[4][2];

    auto phase = [&](int bc, int h, int su, int bd, int vm) {
        if (h == 0) {
#pragma unroll
            for (int i = 0; i < 4; ++i) {
                af[i][0] = *(const s16x8*)&As[bc][(wm * 64 + i * 16 + lr) * 64 + sw0];
                af[i][1] = *(const s16x8*)&As[bc][(wm * 64 + i * 16 + lr) * 64 + sw1];
            }
#pragma unroll
            for (int j = 0; j < 2; ++j) {
                bfr[j][0] = *(const s16x8*)&Bs[bc][(wn * 64 + j * 16 + lr) * 64 + sw0];
                bfr[j][1] = *(const s16x8*)&Bs[bc][(wn * 64 + j * 16 + lr) * 64 + sw1];
            }
        } else {
#pragma unroll
            for (int j = 2; j < 4; ++j) {
                bfr[j][0] = *(const s16x8*)&Bs[bc][(wn * 64 + j * 16 + lr) * 64 + sw0];
                bfr[j][1] = *(const s16x8*)&Bs[bc][(wn * 64 + j * 16 + lr) * 64 + sw1];
            }
        }
        if (su >= 0) stageBatch(su, bd, h);
        BAR();
        __builtin_amdgcn_s_setprio(1);
#pragma unroll
        for (int kk = 0; kk < 2; ++kk)
#pragma unroll
            for (int i = 0; i < 4; ++i)
#pragma unroll
                for (int jj = 0; jj < 2; ++jj) {
                    int j = h * 2 + jj;
                    acc[i][j] = __builtin_amdgcn_mfma_f32_16x16x32_bf16(af[i][kk], bfr[j][kk], acc[i][j], 0, 0, 0);
                }
        __builtin_amdgcn_s_setprio(0);
        if (vm == 6)      asm volatile("s_waitcnt vmcnt(6)" ::: "memory");
        else if (vm == 0) asm volatile("s_waitcnt vmcnt(0)" ::: "memory");
        asm volatile("s_waitcnt lgkmcnt(0)" ::: "memory");
        BAR();
    };

    stageBatch(0, 0, 0); stageBatch(0, 0, 1);
    stageBatch(1, 1, 0); stageBatch(1, 1, 1);
    asm volatile("s_waitcnt vmcnt(6)" ::: "memory");
    BAR();

    for (int t = 0; t < 15; ++t) {
        int u0 = 3 * t;
        phase(0, 0, u0 + 2, 2, -1);
        phase(0, 1, u0 + 2, 2,  6);
        phase(1, 0, u0 + 3, 0, -1);
        phase(1, 1, u0 + 3, 0,  6);
        phase(2, 0, u0 + 4, 1, -1);
        phase(2, 1, u0 + 4, 1,  6);
    }
    phase(0, 0, 47, 2, -1);
    phase(0, 1, 47, 2,  6);
    phase(1, 0, -1, 0, -1);
    phase(1, 1, -1, 0,  0);
    phase(2, 0, -1, 0, -1);
    phase(2, 1, -1, 0, -1);

    const int lg = lane >> 4;
#pragma unroll
    for (int j = 0; j < 4; ++j) {
        int col = col0 + wn * 64 + j * 16 + lr;
        float bias = bskip[col] + bmix[col];
#pragma unroll
        for (int i = 0; i < 4; ++i) {
            int rbase = row0 + wm * 64 + i * 16 + lg * 4;
#pragma unroll
            for (int r = 0; r < 4; ++r)
                out[(size_t)(rbase + r) * DOUT + col] = acc[i][j][r] + bias;
        }
    }
}

extern "C" void kernel_launch(void* const* d_in, const int* in_sizes, int n_in,
                              void* d_out, int out_size, void* d_ws, size_t ws_size,
                              hipStream_t stream) {
    const float* x        = (const float*)d_in[0];
    const float* state_re = (const float*)d_in[1];
    const float* state_im = (const float*)d_in[2];
    const int*   start    = (const int*)d_in[3];
    const float* W_pre    = (const float*)d_in[5];
    const float* b_pre    = (const float*)d_in[6];
    const float* W_skip   = (const float*)d_in[7];
    const float* b_skip   = (const float*)d_in[8];
    const float* W_mix    = (const float*)d_in[9];
    const float* b_mix    = (const float*)d_in[10];
    const float* a_dec    = (const float*)d_in[11];
    const float* b_freq   = (const float*)d_in[12];

    uint8_t* ws = (uint8_t*)d_ws;
    bf16*  A         = (bf16*)(ws);                 // 50331648
    bf16*  Bc        = (bf16*)(ws + 50331648);      // 6291456
    bf16*  Wp        = (bf16*)(ws + 56623104);      // 131072
    float* pre_raw   = (float*)(ws + 56754176);     // 2097152
    float2* local_end= (float2*)(ws + 58851328);    // 1048576
    float2* carry_in = (float2*)(ws + 59899904);    // 1048576
    int*   reset_any = (int*)(ws + 60948480);       // 512

    cvt_wp<<<dim3(64), 256, 0, stream>>>(W_pre, Wp);

    pre_scan1<<<dim3(NCHUNK), 256, 0, stream>>>(x, Wp, A, b_pre, start, a_dec, b_freq,
                                                pre_raw, local_end, reset_any);
    int tail_n = out_size - 8192 * 1024;
    if (tail_n < 0) tail_n = 0;
    if (tail_n > 2048) tail_n = 2048;
    scan_phase2w<<<dim3(16 + 3072), 256, 0, stream>>>(local_end, reset_any, state_re, state_im,
                                                      a_dec, b_freq, carry_in,
                                                      (float*)d_out + 8192 * 1024, tail_n,
                                                      W_skip, W_mix, Bc);
    scan_phase3<<<dim3(NCHUNK), 256, 0, stream>>>(pre_raw, start, a_dec, b_freq, carry_in, A);

    gemm_main<<<dim3(256), 512, 0, stream>>>(A, Bc, b_skip, b_mix, (float*)d_out);
}

// Round 14
// 123.112 us; speedup vs baseline: 1.0835x; 1.0835x over previous
//
#include <hip/hip_runtime.h>
#include <hip/hip_bf16.h>
#include <stdint.h>

#define T_LEN 8192
#define DIN   1024
#define DOUT  1024
#define TRACE 64
#define CTX   16
#define KTOT  3072      // DIN + 2*TRACE*CTX
#define CH    64        // scan chunk length
#define NCHUNK 128      // T_LEN / CH

#define AS1 __attribute__((address_space(1)))
#define AS3 __attribute__((address_space(3)))

// Compile-time-fenced barrier (r9 race fix: intrinsic barrier is not a compiler fence).
#define BAR() asm volatile("s_barrier" ::: "memory")

using bf16 = __hip_bfloat16;
typedef __attribute__((ext_vector_type(4))) float f32x4;
typedef __attribute__((ext_vector_type(8))) short s16x8;

__device__ __forceinline__ void pack4(const float4 v, void* dst) {
    union { bf16 h[4]; uint2 u; } pk;
    pk.h[0] = __float2bfloat16(v.x); pk.h[1] = __float2bfloat16(v.y);
    pk.h[2] = __float2bfloat16(v.z); pk.h[3] = __float2bfloat16(v.w);
    *(uint2*)dst = pk.u;
}

// ---------------- f32 -> bf16: x and W_pre only (weights ride phase2w) ----------------
__global__ void cvt_x(const float* __restrict__ x, const float* __restrict__ Wpre,
                      bf16* __restrict__ A, bf16* __restrict__ Wp) {
    int idx = blockIdx.x * 256 + threadIdx.x;
    if (idx < 2097152) {                       // x: 8192x1024 -> A (ld 3072)
        int r = idx >> 8, c4 = (idx & 255) << 2;
        pack4(*(const float4*)(x + (size_t)r * 1024 + c4), A + (size_t)r * KTOT + c4);
    } else if (idx < 2113536) {                // W_pre: 64x1024 -> Wp (ld 1024)
        int i = idx - 2097152;
        int r = i >> 8, c4 = (i & 255) << 2;
        pack4(*(const float4*)(Wpre + (size_t)r * 1024 + c4), Wp + (size_t)r * 1024 + c4);
    }
}

// ---------------- fused pre-GEMM + scan phase 1 (r10 version) ----------------
__global__ __launch_bounds__(256) void pre_scan1(
    const bf16* __restrict__ A,     // [8192][KTOT], x part (k<1024)
    const bf16* __restrict__ Wp,    // [64][1024]
    const float* __restrict__ bpre,
    const int* __restrict__ start,
    const float* __restrict__ a, const float* __restrict__ bfreq,
    float* __restrict__ pre_raw,    // [8192][64]
    float2* __restrict__ local_end, // [128][1024]
    int* __restrict__ reset_any) {  // [128]
    __shared__ short As[2][64 * 32];
    __shared__ short Bs[2][64 * 32];
    __shared__ float pn[CH][TRACE + 1];
    __shared__ float rn[CH];
    __shared__ int sf[CH];
    const int tid = threadIdx.x, lane = tid & 63, wv = tid >> 6;
    const int row0 = blockIdx.x * 64;
    const int l4 = lane >> 2, c8 = (lane & 3) * 8;

    auto stage = [&](int kt, int buf) {
        int r = wv * 16 + l4;
        const bf16* ga = A + (size_t)(row0 + r) * KTOT + kt * 32 + c8;
        const bf16* gb = Wp + (size_t)r * 1024 + kt * 32 + c8;
        __builtin_amdgcn_global_load_lds(
            (const AS1 void*)ga, (AS3 void*)&As[buf][wv * 512], 16, 0, 0);
        __builtin_amdgcn_global_load_lds(
            (const AS1 void*)gb, (AS3 void*)&Bs[buf][wv * 512], 16, 0, 0);
    };

    f32x4 acc[4];
#pragma unroll
    for (int j = 0; j < 4; ++j) acc[j] = (f32x4)0.0f;

    stage(0, 0);
    __syncthreads();
    int buf = 0;
    const int lr = lane & 15, lk = (lane >> 4) * 8;
    for (int kt = 0; kt < 32; ++kt) {
        if (kt + 1 < 32) stage(kt + 1, buf ^ 1);
        s16x8 af = *(const s16x8*)&As[buf][(wv * 16 + lr) * 32 + lk];
        s16x8 bfr[4];
#pragma unroll
        for (int j = 0; j < 4; ++j)
            bfr[j] = *(const s16x8*)&Bs[buf][(j * 16 + lr) * 32 + lk];
#pragma unroll
        for (int j = 0; j < 4; ++j)
            acc[j] = __builtin_amdgcn_mfma_f32_16x16x32_bf16(af, bfr[j], acc[j], 0, 0, 0);
        __syncthreads();
        buf ^= 1;
    }
    const int lg = lane >> 4;
#pragma unroll
    for (int j = 0; j < 4; ++j) {
        int col = j * 16 + lr;
        float bias = bpre[col];
#pragma unroll
        for (int r = 0; r < 4; ++r) {
            int rl = wv * 16 + lg * 4 + r;
            float v = acc[j][r] + bias;
            pn[rl][col] = v;
            pre_raw[(size_t)(row0 + rl) * TRACE + col] = v;
        }
    }
    if (tid < CH) sf[tid] = start[row0 + tid];
    __syncthreads();
    if (tid < CH) {
        float s = 0.f;
#pragma unroll
        for (int m = 0; m < TRACE; ++m) { float v = pn[tid][m]; s += v * v; }
        rn[tid] = 1.0f / (1e-6f + sqrtf(s));
        int any = __any(sf[tid] != 0);
        if (tid == 0) reset_any[blockIdx.x] = any;
    }
    __syncthreads();
#pragma unroll
    for (int q = 0; q < 4; ++q) {
        int pair = tid + q * 256;
        int m = pair >> 4, c = pair & 15;
        float am = a[m], th = bfreq[c];
        float e = expf(-fabsf(am));
        float sn, cs; sincosf(th, &sn, &cs);
        float gr = e * cs, gi = e * sn;
        float sre = 0.f, sim = 0.f;
        for (int r = 0; r < CH; ++r) {
            float p = pn[r][m] * rn[r];
            if (sf[r]) { sre = p; sim = 0.f; }
            else { float t = gr * sre - gi * sim + p; sim = gr * sim + gi * sre; sre = t; }
        }
        local_end[(size_t)blockIdx.x * 1024 + pair] = make_float2(sre, sim);
    }
}

// ---------------- scan phase 2 (blocks 0-15) + weight cvt (blocks 16+) ----------------
// Carry chain uses 16 CUs; the other ~240 CUs convert W_skip/W_mix -> Bc for free.
__global__ void scan_phase2w(const float2* __restrict__ local_end, const int* __restrict__ reset_any,
                             const float* __restrict__ state_re, const float* __restrict__ state_im,
                             const float* __restrict__ a, const float* __restrict__ bfreq,
                             float2* __restrict__ carry_in, float* __restrict__ out_tail, int tail_n,
                             const float* __restrict__ Wsk, const float* __restrict__ Wmx,
                             bf16* __restrict__ Bc) {
    if (blockIdx.x >= 16) {
        int idx = (blockIdx.x - 16) * 256 + threadIdx.x;  // 786432 quads
        if (idx < 262144) {                // W_skip: 1024x1024 -> Bc (coff 0)
            int r = idx >> 8, c4 = (idx & 255) << 2;
            pack4(*(const float4*)(Wsk + (size_t)r * 1024 + c4), Bc + (size_t)r * KTOT + c4);
        } else {                           // W_mix: 1024x2048 -> Bc (coff 1024)
            int i = idx - 262144;
            int r = i >> 9, c4 = (i & 511) << 2;
            pack4(*(const float4*)(Wmx + (size_t)r * 2048 + c4), Bc + (size_t)r * KTOT + 1024 + c4);
        }
        return;
    }
    if (threadIdx.x >= 64) return;
    const int pair = blockIdx.x * 64 + threadIdx.x;  // 16*64 = 1024
    const int m = pair >> 4, c = pair & 15;
    float am = a[m], th = bfreq[c];
    float e = expf(-64.f * fabsf(am));
    float sn, cs; sincosf(64.f * th, &sn, &cs);
    float gr = e * cs, gi = e * sn;
    float cre = state_re[pair], cim = state_im[pair];

    float2 pf[8]; int rsv[8];
#pragma unroll
    for (int j = 0; j < 8; ++j) { pf[j] = local_end[(size_t)j * 1024 + pair]; rsv[j] = reset_any[j]; }
    for (int kb = 0; kb < NCHUNK; kb += 8) {
        float2 cur[8]; int rs[8];
#pragma unroll
        for (int j = 0; j < 8; ++j) { cur[j] = pf[j]; rs[j] = rsv[j]; }
        if (kb + 8 < NCHUNK) {
#pragma unroll
            for (int j = 0; j < 8; ++j) {
                pf[j]  = local_end[(size_t)(kb + 8 + j) * 1024 + pair];
                rsv[j] = reset_any[kb + 8 + j];
            }
        }
#pragma unroll
        for (int j = 0; j < 8; ++j) {
            carry_in[(size_t)(kb + j) * 1024 + pair] = make_float2(cre, cim);
            if (rs[j]) { cre = cur[j].x; cim = cur[j].y; }
            else {
                float t = gr * cre - gi * cim + cur[j].x;
                cim = gr * cim + gi * cre + cur[j].y;
                cre = t;
            }
        }
    }
    if (pair < tail_n)        out_tail[pair]        = cre;
    if (1024 + pair < tail_n) out_tail[1024 + pair] = cim;
}

// ---------------- scan phase 3: recompute with carry, emit bf16 z_in (4B stores) ----------------
__global__ void scan_phase3(const float* __restrict__ pre_raw, const int* __restrict__ start,
                            const float* __restrict__ a, const float* __restrict__ bfreq,
                            const float2* __restrict__ carry_in, bf16* __restrict__ A) {
    __shared__ float pn[CH][TRACE + 1];
    __shared__ float rn[CH];
    __shared__ int sf[CH];
    const int k = blockIdx.x, tid = threadIdx.x;
    for (int idx = tid; idx < CH * TRACE; idx += 256) {
        int r = idx >> 6, m = idx & 63;
        pn[r][m] = pre_raw[(size_t)(k * CH + r) * TRACE + m];
    }
    if (tid < CH) sf[tid] = start[k * CH + tid];
    __syncthreads();
    if (tid < CH) {
        float s = 0.f;
#pragma unroll
        for (int m = 0; m < TRACE; ++m) { float v = pn[tid][m]; s += v * v; }
        rn[tid] = 1.0f / (1e-6f + sqrtf(s));
    }
    __syncthreads();
#pragma unroll
    for (int q = 0; q < 2; ++q) {
        int p0 = q * 512 + tid * 2;           // even pair: handles (m, c0) and (m, c0+1)
        int m = p0 >> 4, c0 = p0 & 15;
        float am = a[m];
        float e = expf(-fabsf(am));
        float sn0, cs0, sn1, cs1;
        sincosf(bfreq[c0], &sn0, &cs0);
        sincosf(bfreq[c0 + 1], &sn1, &cs1);
        float gr0 = e * cs0, gi0 = e * sn0;
        float gr1 = e * cs1, gi1 = e * sn1;
        float4 ci = *(const float4*)&carry_in[(size_t)k * 1024 + p0];
        float sre0 = ci.x, sim0 = ci.y, sre1 = ci.z, sim1 = ci.w;
        for (int r = 0; r < CH; ++r) {
            float p = pn[r][m] * rn[r];
            if (sf[r]) { sre0 = p; sim0 = 0.f; sre1 = p; sim1 = 0.f; }
            else {
                float t0 = gr0 * sre0 - gi0 * sim0 + p; sim0 = gr0 * sim0 + gi0 * sre0; sre0 = t0;
                float t1 = gr1 * sre1 - gi1 * sim1 + p; sim1 = gr1 * sim1 + gi1 * sre1; sre1 = t1;
            }
            size_t off = (size_t)(k * CH + r) * KTOT + 1024 + m * 32;
            union { bf16 h[2]; uint32_t u; } pr, pi;
            pr.h[0] = __float2bfloat16(sre0); pr.h[1] = __float2bfloat16(sre1);
            pi.h[0] = __float2bfloat16(sim0); pi.h[1] = __float2bfloat16(sim1);
            *(uint32_t*)(A + off + c0)      = pr.u;
            *(uint32_t*)(A + off + 16 + c0) = pi.u;
        }
    }
}

// ---------------- main GEMM (unchanged r10 structure) ----------------
// BM=256 BN=128 BK=64, 512 thr (8 waves 4Mx2N, 64x64/wave), grid 256 = 1 block/CU.
// 2 phases per K-tile, 3 LDS buffers:
//   phase = { ds_reads (cur) ; stage (tile u+2) ; BAR ; setprio(1) 16 MFMA setprio(0) ;
//             [vmcnt(6) at tile end] ; lgkmcnt(0) ; BAR }
__global__ __launch_bounds__(512) void gemm_main(const bf16* __restrict__ A,  // [8192][3072]
                                                 const bf16* __restrict__ B,  // [1024][3072]
                                                 const float* __restrict__ bskip,
                                                 const float* __restrict__ bmix,
                                                 float* __restrict__ out) {   // [8192][1024]
    __shared__ short As[3][256 * 64];   // 96 KB
    __shared__ short Bs[3][128 * 64];   // 48 KB
    const int tid = threadIdx.x;
    const int lane = tid & 63, wv = tid >> 6;
    const int wm = wv >> 1, wn = wv & 1;
    const int wg = blockIdx.x;
    const int xcd = wg & 7, bidx = wg >> 3;          // HW round-robins wg across XCDs
    const int row0 = (xcd * 4 + (bidx >> 3)) * 256;  // 32 row tiles
    const int col0 = (bidx & 7) * 128;               // 8 col tiles

    const int rl8 = lane >> 3;
    const int u8  = lane & 7;
    const int ksw = (u8 ^ rl8) << 3;

    auto stageBatch = [&](int su, int bd, int sb) {
#pragma unroll
        for (int jj = 0; jj < 2; ++jj) {
            int j = sb * 2 + jj;
            int r = wv * 32 + j * 8 + rl8;
            const bf16* ga = A + (size_t)(row0 + r) * KTOT + su * 64 + ksw;
            __builtin_amdgcn_global_load_lds((const AS1 void*)ga,
                (AS3 void*)&As[bd][(wv * 32 + j * 8) * 64], 16, 0, 0);
        }
        int rb = wv * 16 + sb * 8 + rl8;
        const bf16* gb = B + (size_t)(col0 + rb) * KTOT + su * 64 + ksw;
        __builtin_amdgcn_global_load_lds((const AS1 void*)gb,
            (AS3 void*)&Bs[bd][(wv * 16 + sb * 8) * 64], 16, 0, 0);
    };

    f32x4 acc[4][4];
#pragma unroll
    for (int i = 0; i < 4; ++i)
#pragma unroll
        for (int j = 0; j < 4; ++j) acc[i][j] = (f32x4)0.0f;

    const int lr = lane & 15, hi = lane >> 4;
    const int sw0 = ((0 + hi) ^ (lr & 7)) << 3;
    const int sw1 = ((4 + hi) ^ (lr & 7)) << 3;

    s16x8 af[4][2], bfr[4][2];

    auto phase = [&](int bc, int h, int su, int bd, int vm) {
        if (h == 0) {
#pragma unroll
            for (int i = 0; i < 4; ++i) {
                af[i][0] = *(const s16x8*)&As[bc][(wm * 64 + i * 16 + lr) * 64 + sw0];
                af[i][1] = *(const s16x8*)&As[bc][(wm * 64 + i * 16 + lr) * 64 + sw1];
            }
#pragma unroll
            for (int j = 0; j < 2; ++j) {
                bfr[j][0] = *(const s16x8*)&Bs[bc][(wn * 64 + j * 16 + lr) * 64 + sw0];
                bfr[j][1] = *(const s16x8*)&Bs[bc][(wn * 64 + j * 16 + lr) * 64 + sw1];
            }
        } else {
#pragma unroll
            for (int j = 2; j < 4; ++j) {
                bfr[j][0] = *(const s16x8*)&Bs[bc][(wn * 64 + j * 16 + lr) * 64 + sw0];
                bfr[j][1] = *(const s16x8*)&Bs[bc][(wn * 64 + j * 16 + lr) * 64 + sw1];
            }
        }
        if (su >= 0) stageBatch(su, bd, h);
        BAR();
        __builtin_amdgcn_s_setprio(1);
#pragma unroll
        for (int kk = 0; kk < 2; ++kk)
#pragma unroll
            for (int i = 0; i < 4; ++i)
#pragma unroll
                for (int jj = 0; jj < 2; ++jj) {
                    int j = h * 2 + jj;
                    acc[i][j] = __builtin_amdgcn_mfma_f32_16x16x32_bf16(af[i][kk], bfr[j][kk], acc[i][j], 0, 0, 0);
                }
        __builtin_amdgcn_s_setprio(0);
        if (vm == 6)      asm volatile("s_waitcnt vmcnt(6)" ::: "memory");
        else if (vm == 0) asm volatile("s_waitcnt vmcnt(0)" ::: "memory");
        asm volatile("s_waitcnt lgkmcnt(0)" ::: "memory");
        BAR();
    };

    stageBatch(0, 0, 0); stageBatch(0, 0, 1);
    stageBatch(1, 1, 0); stageBatch(1, 1, 1);
    asm volatile("s_waitcnt vmcnt(6)" ::: "memory");
    BAR();

    for (int t = 0; t < 15; ++t) {
        int u0 = 3 * t;
        phase(0, 0, u0 + 2, 2, -1);
        phase(0, 1, u0 + 2, 2,  6);
        phase(1, 0, u0 + 3, 0, -1);
        phase(1, 1, u0 + 3, 0,  6);
        phase(2, 0, u0 + 4, 1, -1);
        phase(2, 1, u0 + 4, 1,  6);
    }
    phase(0, 0, 47, 2, -1);
    phase(0, 1, 47, 2,  6);
    phase(1, 0, -1, 0, -1);
    phase(1, 1, -1, 0,  0);
    phase(2, 0, -1, 0, -1);
    phase(2, 1, -1, 0, -1);

    const int lg = lane >> 4;
#pragma unroll
    for (int j = 0; j < 4; ++j) {
        int col = col0 + wn * 64 + j * 16 + lr;
        float bias = bskip[col] + bmix[col];
#pragma unroll
        for (int i = 0; i < 4; ++i) {
            int rbase = row0 + wm * 64 + i * 16 + lg * 4;
#pragma unroll
            for (int r = 0; r < 4; ++r)
                out[(size_t)(rbase + r) * DOUT + col] = acc[i][j][r] + bias;
        }
    }
}

extern "C" void kernel_launch(void* const* d_in, const int* in_sizes, int n_in,
                              void* d_out, int out_size, void* d_ws, size_t ws_size,
                              hipStream_t stream) {
    const float* x        = (const float*)d_in[0];
    const float* state_re = (const float*)d_in[1];
    const float* state_im = (const float*)d_in[2];
    const int*   start    = (const int*)d_in[3];
    const float* W_pre    = (const float*)d_in[5];
    const float* b_pre    = (const float*)d_in[6];
    const float* W_skip   = (const float*)d_in[7];
    const float* b_skip   = (const float*)d_in[8];
    const float* W_mix    = (const float*)d_in[9];
    const float* b_mix    = (const float*)d_in[10];
    const float* a_dec    = (const float*)d_in[11];
    const float* b_freq   = (const float*)d_in[12];

    uint8_t* ws = (uint8_t*)d_ws;
    bf16*  A         = (bf16*)(ws);                 // 50331648
    bf16*  Bc        = (bf16*)(ws + 50331648);      // 6291456
    bf16*  Wp        = (bf16*)(ws + 56623104);      // 131072
    float* pre_raw   = (float*)(ws + 56754176);     // 2097152
    float2* local_end= (float2*)(ws + 58851328);    // 1048576
    float2* carry_in = (float2*)(ws + 59899904);    // 1048576
    int*   reset_any = (int*)(ws + 60948480);       // 512

    cvt_x<<<dim3((2113536 + 255) / 256), 256, 0, stream>>>(x, W_pre, A, Wp);

    pre_scan1<<<dim3(NCHUNK), 256, 0, stream>>>(A, Wp, b_pre, start, a_dec, b_freq,
                                                pre_raw, local_end, reset_any);
    int tail_n = out_size - 8192 * 1024;
    if (tail_n < 0) tail_n = 0;
    if (tail_n > 2048) tail_n = 2048;
    scan_phase2w<<<dim3(16 + 3072), 256, 0, stream>>>(local_end, reset_any, state_re, state_im,
                                                      a_dec, b_freq, carry_in,
                                                      (float*)d_out + 8192 * 1024, tail_n,
                                                      W_skip, W_mix, Bc);
    scan_phase3<<<dim3(NCHUNK), 256, 0, stream>>>(pre_raw, start, a_dec, b_freq, carry_in, A);

    gemm_main<<<dim3(256), 512, 0, stream>>>(A, Bc, b_skip, b_mix, (float*)d_out);
}

// Round 15
// 119.252 us; speedup vs baseline: 1.1186x; 1.0324x over previous
//
#include <hip/hip_runtime.h>
#include <hip/hip_bf16.h>
#include <stdint.h>

#define T_LEN 8192
#define DIN   1024
#define DOUT  1024
#define TRACE 64
#define CTX   16
#define KTOT  3072      // DIN + 2*TRACE*CTX
#define CH    64        // scan chunk length
#define NCHUNK 128      // T_LEN / CH

#define AS1 __attribute__((address_space(1)))
#define AS3 __attribute__((address_space(3)))

// Compile-time-fenced barrier (r9 race fix: intrinsic barrier is not a compiler fence).
#define BAR() asm volatile("s_barrier" ::: "memory")

using bf16 = __hip_bfloat16;
typedef __attribute__((ext_vector_type(4))) float f32x4;
typedef __attribute__((ext_vector_type(8))) short s16x8;

__device__ __forceinline__ void pack4(const float4 v, void* dst) {
    union { bf16 h[4]; uint2 u; } pk;
    pk.h[0] = __float2bfloat16(v.x); pk.h[1] = __float2bfloat16(v.y);
    pk.h[2] = __float2bfloat16(v.z); pk.h[3] = __float2bfloat16(v.w);
    *(uint2*)dst = pk.u;
}

// ---------------- f32 -> bf16: x and W_pre only (weights ride phase2w) ----------------
__global__ void cvt_x(const float* __restrict__ x, const float* __restrict__ Wpre,
                      bf16* __restrict__ A, bf16* __restrict__ Wp) {
    int idx = blockIdx.x * 256 + threadIdx.x;
    if (idx < 2097152) {                       // x: 8192x1024 -> A (ld 3072)
        int r = idx >> 8, c4 = (idx & 255) << 2;
        pack4(*(const float4*)(x + (size_t)r * 1024 + c4), A + (size_t)r * KTOT + c4);
    } else if (idx < 2113536) {                // W_pre: 64x1024 -> Wp (ld 1024)
        int i = idx - 2097152;
        int r = i >> 8, c4 = (i & 255) << 2;
        pack4(*(const float4*)(Wpre + (size_t)r * 1024 + c4), Wp + (size_t)r * 1024 + c4);
    }
}

// ---------------- fused pre-GEMM + scan phase 1 (r10 version) ----------------
__global__ __launch_bounds__(256) void pre_scan1(
    const bf16* __restrict__ A,     // [8192][KTOT], x part (k<1024)
    const bf16* __restrict__ Wp,    // [64][1024]
    const float* __restrict__ bpre,
    const int* __restrict__ start,
    const float* __restrict__ a, const float* __restrict__ bfreq,
    float* __restrict__ pre_raw,    // [8192][64]
    float2* __restrict__ local_end, // [128][1024]
    int* __restrict__ reset_any) {  // [128]
    __shared__ short As[2][64 * 32];
    __shared__ short Bs[2][64 * 32];
    __shared__ float pn[CH][TRACE + 1];
    __shared__ float rn[CH];
    __shared__ int sf[CH];
    const int tid = threadIdx.x, lane = tid & 63, wv = tid >> 6;
    const int row0 = blockIdx.x * 64;
    const int l4 = lane >> 2, c8 = (lane & 3) * 8;

    auto stage = [&](int kt, int buf) {
        int r = wv * 16 + l4;
        const bf16* ga = A + (size_t)(row0 + r) * KTOT + kt * 32 + c8;
        const bf16* gb = Wp + (size_t)r * 1024 + kt * 32 + c8;
        __builtin_amdgcn_global_load_lds(
            (const AS1 void*)ga, (AS3 void*)&As[buf][wv * 512], 16, 0, 0);
        __builtin_amdgcn_global_load_lds(
            (const AS1 void*)gb, (AS3 void*)&Bs[buf][wv * 512], 16, 0, 0);
    };

    f32x4 acc[4];
#pragma unroll
    for (int j = 0; j < 4; ++j) acc[j] = (f32x4)0.0f;

    stage(0, 0);
    __syncthreads();
    int buf = 0;
    const int lr = lane & 15, lk = (lane >> 4) * 8;
    for (int kt = 0; kt < 32; ++kt) {
        if (kt + 1 < 32) stage(kt + 1, buf ^ 1);
        s16x8 af = *(const s16x8*)&As[buf][(wv * 16 + lr) * 32 + lk];
        s16x8 bfr[4];
#pragma unroll
        for (int j = 0; j < 4; ++j)
            bfr[j] = *(const s16x8*)&Bs[buf][(j * 16 + lr) * 32 + lk];
#pragma unroll
        for (int j = 0; j < 4; ++j)
            acc[j] = __builtin_amdgcn_mfma_f32_16x16x32_bf16(af, bfr[j], acc[j], 0, 0, 0);
        __syncthreads();
        buf ^= 1;
    }
    const int lg = lane >> 4;
#pragma unroll
    for (int j = 0; j < 4; ++j) {
        int col = j * 16 + lr;
        float bias = bpre[col];
#pragma unroll
        for (int r = 0; r < 4; ++r) {
            int rl = wv * 16 + lg * 4 + r;
            float v = acc[j][r] + bias;
            pn[rl][col] = v;
            pre_raw[(size_t)(row0 + rl) * TRACE + col] = v;
        }
    }
    if (tid < CH) sf[tid] = start[row0 + tid];
    __syncthreads();
    if (tid < CH) {
        float s = 0.f;
#pragma unroll
        for (int m = 0; m < TRACE; ++m) { float v = pn[tid][m]; s += v * v; }
        rn[tid] = 1.0f / (1e-6f + sqrtf(s));
        int any = __any(sf[tid] != 0);
        if (tid == 0) reset_any[blockIdx.x] = any;
    }
    __syncthreads();
#pragma unroll
    for (int q = 0; q < 4; ++q) {
        int pair = tid + q * 256;
        int m = pair >> 4, c = pair & 15;
        float am = a[m], th = bfreq[c];
        float e = expf(-fabsf(am));
        float sn, cs; sincosf(th, &sn, &cs);
        float gr = e * cs, gi = e * sn;
        float sre = 0.f, sim = 0.f;
        for (int r = 0; r < CH; ++r) {
            float p = pn[r][m] * rn[r];
            if (sf[r]) { sre = p; sim = 0.f; }
            else { float t = gr * sre - gi * sim + p; sim = gr * sim + gi * sre; sre = t; }
        }
        local_end[(size_t)blockIdx.x * 1024 + pair] = make_float2(sre, sim);
    }
}

// ---------------- scan phase 2 (blocks 0-15) + weight cvt (blocks 16+) ----------------
// Carry chain uses 16 CUs; the other ~240 CUs convert W_skip/W_mix -> Bc for free.
__global__ void scan_phase2w(const float2* __restrict__ local_end, const int* __restrict__ reset_any,
                             const float* __restrict__ state_re, const float* __restrict__ state_im,
                             const float* __restrict__ a, const float* __restrict__ bfreq,
                             float2* __restrict__ carry_in, float* __restrict__ out_tail, int tail_n,
                             const float* __restrict__ Wsk, const float* __restrict__ Wmx,
                             bf16* __restrict__ Bc) {
    if (blockIdx.x >= 16) {
        int idx = (blockIdx.x - 16) * 256 + threadIdx.x;  // 786432 quads
        if (idx < 262144) {                // W_skip: 1024x1024 -> Bc (coff 0)
            int r = idx >> 8, c4 = (idx & 255) << 2;
            pack4(*(const float4*)(Wsk + (size_t)r * 1024 + c4), Bc + (size_t)r * KTOT + c4);
        } else {                           // W_mix: 1024x2048 -> Bc (coff 1024)
            int i = idx - 262144;
            int r = i >> 9, c4 = (i & 511) << 2;
            pack4(*(const float4*)(Wmx + (size_t)r * 2048 + c4), Bc + (size_t)r * KTOT + 1024 + c4);
        }
        return;
    }
    if (threadIdx.x >= 64) return;
    const int pair = blockIdx.x * 64 + threadIdx.x;  // 16*64 = 1024
    const int m = pair >> 4, c = pair & 15;
    float am = a[m], th = bfreq[c];
    float e = expf(-64.f * fabsf(am));
    float sn, cs; sincosf(64.f * th, &sn, &cs);
    float gr = e * cs, gi = e * sn;
    float cre = state_re[pair], cim = state_im[pair];

    float2 pf[8]; int rsv[8];
#pragma unroll
    for (int j = 0; j < 8; ++j) { pf[j] = local_end[(size_t)j * 1024 + pair]; rsv[j] = reset_any[j]; }
    for (int kb = 0; kb < NCHUNK; kb += 8) {
        float2 cur[8]; int rs[8];
#pragma unroll
        for (int j = 0; j < 8; ++j) { cur[j] = pf[j]; rs[j] = rsv[j]; }
        if (kb + 8 < NCHUNK) {
#pragma unroll
            for (int j = 0; j < 8; ++j) {
                pf[j]  = local_end[(size_t)(kb + 8 + j) * 1024 + pair];
                rsv[j] = reset_any[kb + 8 + j];
            }
        }
#pragma unroll
        for (int j = 0; j < 8; ++j) {
            carry_in[(size_t)(kb + j) * 1024 + pair] = make_float2(cre, cim);
            if (rs[j]) { cre = cur[j].x; cim = cur[j].y; }
            else {
                float t = gr * cre - gi * cim + cur[j].x;
                cim = gr * cim + gi * cre + cur[j].y;
                cre = t;
            }
        }
    }
    if (pair < tail_n)        out_tail[pair]        = cre;
    if (1024 + pair < tail_n) out_tail[1024 + pair] = cim;
}

// ---------------- scan phase 3: 256 blocks — chunk k = b>>1, pair-half h = b&1 ----------------
// Each block recomputes the chunk's norms (cheap, 16 KB) and scans 512 pairs:
// doubles CU coverage vs the 128-block version with identical serial-chain length.
__global__ void scan_phase3(const float* __restrict__ pre_raw, const int* __restrict__ start,
                            const float* __restrict__ a, const float* __restrict__ bfreq,
                            const float2* __restrict__ carry_in, bf16* __restrict__ A) {
    __shared__ float pn[CH][TRACE + 1];
    __shared__ float rn[CH];
    __shared__ int sf[CH];
    const int k = blockIdx.x >> 1, h = blockIdx.x & 1, tid = threadIdx.x;
    for (int idx = tid; idx < CH * TRACE; idx += 256) {
        int r = idx >> 6, m = idx & 63;
        pn[r][m] = pre_raw[(size_t)(k * CH + r) * TRACE + m];
    }
    if (tid < CH) sf[tid] = start[k * CH + tid];
    __syncthreads();
    if (tid < CH) {
        float s = 0.f;
#pragma unroll
        for (int m = 0; m < TRACE; ++m) { float v = pn[tid][m]; s += v * v; }
        rn[tid] = 1.0f / (1e-6f + sqrtf(s));
    }
    __syncthreads();
    {
        int p0 = h * 512 + tid * 2;           // this block covers pairs [h*512, h*512+512)
        int m = p0 >> 4, c0 = p0 & 15;
        float am = a[m];
        float e = expf(-fabsf(am));
        float sn0, cs0, sn1, cs1;
        sincosf(bfreq[c0], &sn0, &cs0);
        sincosf(bfreq[c0 + 1], &sn1, &cs1);
        float gr0 = e * cs0, gi0 = e * sn0;
        float gr1 = e * cs1, gi1 = e * sn1;
        float4 ci = *(const float4*)&carry_in[(size_t)k * 1024 + p0];
        float sre0 = ci.x, sim0 = ci.y, sre1 = ci.z, sim1 = ci.w;
        for (int r = 0; r < CH; ++r) {
            float p = pn[r][m] * rn[r];
            if (sf[r]) { sre0 = p; sim0 = 0.f; sre1 = p; sim1 = 0.f; }
            else {
                float t0 = gr0 * sre0 - gi0 * sim0 + p; sim0 = gr0 * sim0 + gi0 * sre0; sre0 = t0;
                float t1 = gr1 * sre1 - gi1 * sim1 + p; sim1 = gr1 * sim1 + gi1 * sre1; sre1 = t1;
            }
            size_t off = (size_t)(k * CH + r) * KTOT + 1024 + m * 32;
            union { bf16 h2[2]; uint32_t u; } pr, pi;
            pr.h2[0] = __float2bfloat16(sre0); pr.h2[1] = __float2bfloat16(sre1);
            pi.h2[0] = __float2bfloat16(sim0); pi.h2[1] = __float2bfloat16(sim1);
            *(uint32_t*)(A + off + c0)      = pr.u;
            *(uint32_t*)(A + off + 16 + c0) = pi.u;
        }
    }
}

// ---------------- main GEMM (unchanged r10 structure) ----------------
// BM=256 BN=128 BK=64, 512 thr (8 waves 4Mx2N, 64x64/wave), grid 256 = 1 block/CU.
// 2 phases per K-tile, 3 LDS buffers:
//   phase = { ds_reads (cur) ; stage (tile u+2) ; BAR ; setprio(1) 16 MFMA setprio(0) ;
//             [vmcnt(6) at tile end] ; lgkmcnt(0) ; BAR }
__global__ __launch_bounds__(512) void gemm_main(const bf16* __restrict__ A,  // [8192][3072]
                                                 const bf16* __restrict__ B,  // [1024][3072]
                                                 const float* __restrict__ bskip,
                                                 const float* __restrict__ bmix,
                                                 float* __restrict__ out) {   // [8192][1024]
    __shared__ short As[3][256 * 64];   // 96 KB
    __shared__ short Bs[3][128 * 64];   // 48 KB
    const int tid = threadIdx.x;
    const int lane = tid & 63, wv = tid >> 6;
    const int wm = wv >> 1, wn = wv & 1;
    const int wg = blockIdx.x;
    const int xcd = wg & 7, bidx = wg >> 3;          // HW round-robins wg across XCDs
    const int row0 = (xcd * 4 + (bidx >> 3)) * 256;  // 32 row tiles
    const int col0 = (bidx & 7) * 128;               // 8 col tiles

    const int rl8 = lane >> 3;
    const int u8  = lane & 7;
    const int ksw = (u8 ^ rl8) << 3;

    auto stageBatch = [&](int su, int bd, int sb) {
#pragma unroll
        for (int jj = 0; jj < 2; ++jj) {
            int j = sb * 2 + jj;
            int r = wv * 32 + j * 8 + rl8;
            const bf16* ga = A + (size_t)(row0 + r) * KTOT + su * 64 + ksw;
            __builtin_amdgcn_global_load_lds((const AS1 void*)ga,
                (AS3 void*)&As[bd][(wv * 32 + j * 8) * 64], 16, 0, 0);
        }
        int rb = wv * 16 + sb * 8 + rl8;
        const bf16* gb = B + (size_t)(col0 + rb) * KTOT + su * 64 + ksw;
        __builtin_amdgcn_global_load_lds((const AS1 void*)gb,
            (AS3 void*)&Bs[bd][(wv * 16 + sb * 8) * 64], 16, 0, 0);
    };

    f32x4 acc[4][4];
#pragma unroll
    for (int i = 0; i < 4; ++i)
#pragma unroll
        for (int j = 0; j < 4; ++j) acc[i][j] = (f32x4)0.0f;

    const int lr = lane & 15, hi = lane >> 4;
    const int sw0 = ((0 + hi) ^ (lr & 7)) << 3;
    const int sw1 = ((4 + hi) ^ (lr & 7)) << 3;

    s16x8 af[4][2], bfr[4][2];

    auto phase = [&](int bc, int h, int su, int bd, int vm) {
        if (h == 0) {
#pragma unroll
            for (int i = 0; i < 4; ++i) {
                af[i][0] = *(const s16x8*)&As[bc][(wm * 64 + i * 16 + lr) * 64 + sw0];
                af[i][1] = *(const s16x8*)&As[bc][(wm * 64 + i * 16 + lr) * 64 + sw1];
            }
#pragma unroll
            for (int j = 0; j < 2; ++j) {
                bfr[j][0] = *(const s16x8*)&Bs[bc][(wn * 64 + j * 16 + lr) * 64 + sw0];
                bfr[j][1] = *(const s16x8*)&Bs[bc][(wn * 64 + j * 16 + lr) * 64 + sw1];
            }
        } else {
#pragma unroll
            for (int j = 2; j < 4; ++j) {
                bfr[j][0] = *(const s16x8*)&Bs[bc][(wn * 64 + j * 16 + lr) * 64 + sw0];
                bfr[j][1] = *(const s16x8*)&Bs[bc][(wn * 64 + j * 16 + lr) * 64 + sw1];
            }
        }
        if (su >= 0) stageBatch(su, bd, h);
        BAR();
        __builtin_amdgcn_s_setprio(1);
#pragma unroll
        for (int kk = 0; kk < 2; ++kk)
#pragma unroll
            for (int i = 0; i < 4; ++i)
#pragma unroll
                for (int jj = 0; jj < 2; ++jj) {
                    int j = h * 2 + jj;
                    acc[i][j] = __builtin_amdgcn_mfma_f32_16x16x32_bf16(af[i][kk], bfr[j][kk], acc[i][j], 0, 0, 0);
                }
        __builtin_amdgcn_s_setprio(0);
        if (vm == 6)      asm volatile("s_waitcnt vmcnt(6)" ::: "memory");
        else if (vm == 0) asm volatile("s_waitcnt vmcnt(0)" ::: "memory");
        asm volatile("s_waitcnt lgkmcnt(0)" ::: "memory");
        BAR();
    };

    stageBatch(0, 0, 0); stageBatch(0, 0, 1);
    stageBatch(1, 1, 0); stageBatch(1, 1, 1);
    asm volatile("s_waitcnt vmcnt(6)" ::: "memory");
    BAR();

    for (int t = 0; t < 15; ++t) {
        int u0 = 3 * t;
        phase(0, 0, u0 + 2, 2, -1);
        phase(0, 1, u0 + 2, 2,  6);
        phase(1, 0, u0 + 3, 0, -1);
        phase(1, 1, u0 + 3, 0,  6);
        phase(2, 0, u0 + 4, 1, -1);
        phase(2, 1, u0 + 4, 1,  6);
    }
    phase(0, 0, 47, 2, -1);
    phase(0, 1, 47, 2,  6);
    phase(1, 0, -1, 0, -1);
    phase(1, 1, -1, 0,  0);
    phase(2, 0, -1, 0, -1);
    phase(2, 1, -1, 0, -1);

    const int lg = lane >> 4;
#pragma unroll
    for (int j = 0; j < 4; ++j) {
        int col = col0 + wn * 64 + j * 16 + lr;
        float bias = bskip[col] + bmix[col];
#pragma unroll
        for (int i = 0; i < 4; ++i) {
            int rbase = row0 + wm * 64 + i * 16 + lg * 4;
#pragma unroll
            for (int r = 0; r < 4; ++r)
                out[(size_t)(rbase + r) * DOUT + col] = acc[i][j][r] + bias;
        }
    }
}

extern "C" void kernel_launch(void* const* d_in, const int* in_sizes, int n_in,
                              void* d_out, int out_size, void* d_ws, size_t ws_size,
                              hipStream_t stream) {
    const float* x        = (const float*)d_in[0];
    const float* state_re = (const float*)d_in[1];
    const float* state_im = (const float*)d_in[2];
    const int*   start    = (const int*)d_in[3];
    const float* W_pre    = (const float*)d_in[5];
    const float* b_pre    = (const float*)d_in[6];
    const float* W_skip   = (const float*)d_in[7];
    const float* b_skip   = (const float*)d_in[8];
    const float* W_mix    = (const float*)d_in[9];
    const float* b_mix    = (const float*)d_in[10];
    const float* a_dec    = (const float*)d_in[11];
    const float* b_freq   = (const float*)d_in[12];

    uint8_t* ws = (uint8_t*)d_ws;
    bf16*  A         = (bf16*)(ws);                 // 50331648
    bf16*  Bc        = (bf16*)(ws + 50331648);      // 6291456
    bf16*  Wp        = (bf16*)(ws + 56623104);      // 131072
    float* pre_raw   = (float*)(ws + 56754176);     // 2097152
    float2* local_end= (float2*)(ws + 58851328);    // 1048576
    float2* carry_in = (float2*)(ws + 59899904);    // 1048576
    int*   reset_any = (int*)(ws + 60948480);       // 512

    cvt_x<<<dim3((2113536 + 255) / 256), 256, 0, stream>>>(x, W_pre, A, Wp);

    pre_scan1<<<dim3(NCHUNK), 256, 0, stream>>>(A, Wp, b_pre, start, a_dec, b_freq,
                                                pre_raw, local_end, reset_any);
    int tail_n = out_size - 8192 * 1024;
    if (tail_n < 0) tail_n = 0;
    if (tail_n > 2048) tail_n = 2048;
    scan_phase2w<<<dim3(16 + 3072), 256, 0, stream>>>(local_end, reset_any, state_re, state_im,
                                                      a_dec, b_freq, carry_in,
                                                      (float*)d_out + 8192 * 1024, tail_n,
                                                      W_skip, W_mix, Bc);
    scan_phase3<<<dim3(2 * NCHUNK), 256, 0, stream>>>(pre_raw, start, a_dec, b_freq, carry_in, A);

    gemm_main<<<dim3(256), 512, 0, stream>>>(A, Bc, b_skip, b_mix, (float*)d_out);
}